// Round 2
// baseline (183.386 us; speedup 1.0000x reference)
//
#include <hip/hip_runtime.h>

#define DIM 16
#define SEQ 2048
#define CHUNK 512            // keys per wave (SEQ / 4 waves)
#define ROWS_PER_BLOCK 64    // one row per lane

// ---------------- quantum circuit primitives (all register-resident) --------

template<int P>
__device__ __forceinline__ void rx_bit(float sr[DIM], float si[DIM], float ch, float sh) {
    constexpr int m = 1 << P;
    #pragma unroll
    for (int i = 0; i < DIM; ++i) {
        if ((i & m) == 0) {
            const int j = i | m;
            float r0 = sr[i], i0 = si[i], r1 = sr[j], i1 = si[j];
            sr[i] = fmaf(ch, r0,  sh * i1);
            si[i] = fmaf(ch, i0, -sh * r1);
            sr[j] = fmaf(ch, r1,  sh * i0);
            si[j] = fmaf(ch, i1, -sh * r0);
        }
    }
}

template<int PC, int PT>
__device__ __forceinline__ void cnot_g(float sr[DIM], float si[DIM]) {
    constexpr int cm = 1 << PC, tm = 1 << PT;
    #pragma unroll
    for (int i = 0; i < DIM; ++i) {
        if ((i & cm) && !(i & tm)) {
            const int j = i | tm;
            float t;
            t = sr[i]; sr[i] = sr[j]; sr[j] = t;
            t = si[i]; si[i] = si[j]; si[j] = t;
        }
    }
}

__device__ __forceinline__ void embed(float sr[DIM], float si[DIM], float4 a) {
    #pragma unroll
    for (int i = 0; i < DIM; ++i) { sr[i] = 0.f; si[i] = 0.f; }
    sr[0] = 1.f;
    float ch, sh;
    __sincosf(0.5f * a.x, &sh, &ch); rx_bit<3>(sr, si, ch, sh);   // wire 0 -> bit 3
    __sincosf(0.5f * a.y, &sh, &ch); rx_bit<2>(sr, si, ch, sh);
    __sincosf(0.5f * a.z, &sh, &ch); rx_bit<1>(sr, si, ch, sh);
    __sincosf(0.5f * a.w, &sh, &ch); rx_bit<0>(sr, si, ch, sh);
}

__device__ __forceinline__ void layer(float sr[DIM], float si[DIM], float4 w) {
    float ch, sh;
    __sincosf(0.5f * w.x, &sh, &ch); rx_bit<3>(sr, si, ch, sh);
    __sincosf(0.5f * w.y, &sh, &ch); rx_bit<2>(sr, si, ch, sh);
    __sincosf(0.5f * w.z, &sh, &ch); rx_bit<1>(sr, si, ch, sh);
    __sincosf(0.5f * w.w, &sh, &ch); rx_bit<0>(sr, si, ch, sh);
    cnot_g<3,2>(sr, si);
    cnot_g<2,1>(sr, si);
    cnot_g<1,0>(sr, si);
    cnot_g<0,3>(sr, si);
}

__device__ __forceinline__ float4 measure(const float sr[DIM], const float si[DIM]) {
    float e0 = 0.f, e1 = 0.f, e2 = 0.f, e3 = 0.f;
    #pragma unroll
    for (int i = 0; i < DIM; ++i) {
        float p = fmaf(sr[i], sr[i], si[i] * si[i]);
        e0 += (i & 8) ? -p : p;
        e1 += (i & 4) ? -p : p;
        e2 += (i & 2) ? -p : p;
        e3 += (i & 1) ? -p : p;
    }
    return make_float4(e0, e1, e2, e3);
}

// ---------------- kernel 1: Q,K,V circuits (split over blockIdx.y) ---------

__global__ __launch_bounds__(256) void qkv_kernel(
        const float* __restrict__ x,
        const float* __restrict__ wQp, const float* __restrict__ wKp,
        const float* __restrict__ wVp,
        float4* __restrict__ Q, float4* __restrict__ KV, int n) {
    const int i = blockIdx.x * 256 + threadIdx.x;
    const int which = blockIdx.y;          // 0=Q, 1=K, 2=V
    const float4 xv = ((const float4*)x)[i];
    const float* wp = (which == 0) ? wQp : (which == 1) ? wKp : wVp;
    const float4 w = *(const float4*)wp;

    float sr[DIM], si[DIM];
    embed(sr, si, xv);
    layer(sr, si, w);
    const float4 r = measure(sr, si);

    if (which == 0)      Q[i]          = r;
    else if (which == 1) KV[2 * i]     = r;   // K interleaved with V
    else                 KV[2 * i + 1] = r;
}

// ---------------- kernel 2: attention + final circuit ----------------------
// Block = 256 threads = 4 waves. Wave w handles key-chunk w (512 keys) for
// 64 rows (one per lane). Partials combined through a tiny LDS buffer, then
// wave 0 runs the fused final circuit.

__global__ __launch_bounds__(256) void attn_kernel(
        const float4* __restrict__ Q, const float4* __restrict__ KV,
        const float* __restrict__ wCp, float4* __restrict__ out) {
    __shared__ float part[4][ROWS_PER_BLOCK][5];   // stride 5: conflict-free

    const int b    = blockIdx.x >> 5;              // 32 row-blocks per batch
    const int rb   = blockIdx.x & 31;
    const int wave = threadIdx.x >> 6;
    const int lane = threadIdx.x & 63;

    const int row = b * SEQ + rb * ROWS_PER_BLOCK + lane;
    const float4 q = Q[row];
    // fold 0.5 (1/sqrt(E)) * log2(e) so the loop uses exp2 directly
    const float SC = 0.72134752044f;
    const float qx = q.x * SC, qy = q.y * SC, qz = q.z * SC, qw = q.w * SC;

    const float4* KVb = KV + (size_t)b * (2 * SEQ) + wave * (2 * CHUNK);

    float den = 0.f, a0 = 0.f, a1 = 0.f, a2 = 0.f, a3 = 0.f;
    #pragma unroll 8
    for (int k = 0; k < CHUNK; ++k) {
        const float4 kv = KVb[2 * k];       // wave-uniform addr -> broadcast
        const float4 vv = KVb[2 * k + 1];   // same 32B line
        float s = fmaf(qx, kv.x, fmaf(qy, kv.y, fmaf(qz, kv.z, qw * kv.w)));
        float e = exp2f(s);                 // s in [-2.89,2.89]: no max needed
        den += e;
        a0 = fmaf(e, vv.x, a0);
        a1 = fmaf(e, vv.y, a1);
        a2 = fmaf(e, vv.z, a2);
        a3 = fmaf(e, vv.w, a3);
    }
    part[wave][lane][0] = den;
    part[wave][lane][1] = a0;
    part[wave][lane][2] = a1;
    part[wave][lane][3] = a2;
    part[wave][lane][4] = a3;
    __syncthreads();

    if (threadIdx.x < ROWS_PER_BLOCK) {
        const int r = threadIdx.x;
        float d  = part[0][r][0] + part[1][r][0] + part[2][r][0] + part[3][r][0];
        float c0 = part[0][r][1] + part[1][r][1] + part[2][r][1] + part[3][r][1];
        float c1 = part[0][r][2] + part[1][r][2] + part[2][r][2] + part[3][r][2];
        float c2 = part[0][r][3] + part[1][r][3] + part[2][r][3] + part[3][r][3];
        float c3 = part[0][r][4] + part[1][r][4] + part[2][r][4] + part[3][r][4];
        const float inv = 1.0f / d;
        const float4 ctx = make_float4(c0 * inv, c1 * inv, c2 * inv, c3 * inv);

        const float4 wC = *(const float4*)wCp;
        float sr[DIM], si[DIM];
        embed(sr, si, ctx);
        layer(sr, si, wC);
        out[b * SEQ + rb * ROWS_PER_BLOCK + r] = measure(sr, si);
    }
}

// ---------------- launch ---------------------------------------------------

extern "C" void kernel_launch(void* const* d_in, const int* in_sizes, int n_in,
                              void* d_out, int out_size, void* d_ws, size_t ws_size,
                              hipStream_t stream) {
    const float* x  = (const float*)d_in[0];
    const float* wQ = (const float*)d_in[1];
    const float* wK = (const float*)d_in[2];
    const float* wV = (const float*)d_in[3];
    const float* wC = (const float*)d_in[4];

    const int n = in_sizes[0] / 4;          // B*S = 65536 rows
    float4* Q  = (float4*)d_ws;             // n float4        = 1 MB
    float4* KV = Q + n;                     // 2n float4       = 2 MB (K,V interleaved)

    dim3 qgrid(n / 256, 3);
    qkv_kernel<<<qgrid, 256, 0, stream>>>(x, wQ, wK, wV, Q, KV, n);

    const int blocks = n / ROWS_PER_BLOCK;  // 1024
    attn_kernel<<<blocks, 256, 0, stream>>>(Q, KV, wC, (float4*)d_out);
}

// Round 3
// 123.368 us; speedup vs baseline: 1.4865x; 1.4865x over previous
//
#include <hip/hip_runtime.h>

#define DIM 16
#define SEQ 2048
#define CHUNK 512            // keys per block chunk
#define NCHUNK 4             // SEQ / CHUNK

// ---------------- quantum circuit primitives (all register-resident) --------

template<int P>
__device__ __forceinline__ void rx_bit(float sr[DIM], float si[DIM], float ch, float sh) {
    constexpr int m = 1 << P;
    #pragma unroll
    for (int i = 0; i < DIM; ++i) {
        if ((i & m) == 0) {
            const int j = i | m;
            float r0 = sr[i], i0 = si[i], r1 = sr[j], i1 = si[j];
            sr[i] = fmaf(ch, r0,  sh * i1);
            si[i] = fmaf(ch, i0, -sh * r1);
            sr[j] = fmaf(ch, r1,  sh * i0);
            si[j] = fmaf(ch, i1, -sh * r0);
        }
    }
}

template<int PC, int PT>
__device__ __forceinline__ void cnot_g(float sr[DIM], float si[DIM]) {
    constexpr int cm = 1 << PC, tm = 1 << PT;
    #pragma unroll
    for (int i = 0; i < DIM; ++i) {
        if ((i & cm) && !(i & tm)) {
            const int j = i | tm;
            float t;
            t = sr[i]; sr[i] = sr[j]; sr[j] = t;
            t = si[i]; si[i] = si[j]; si[j] = t;
        }
    }
}

__device__ __forceinline__ void embed(float sr[DIM], float si[DIM], float4 a) {
    #pragma unroll
    for (int i = 0; i < DIM; ++i) { sr[i] = 0.f; si[i] = 0.f; }
    sr[0] = 1.f;
    float ch, sh;
    __sincosf(0.5f * a.x, &sh, &ch); rx_bit<3>(sr, si, ch, sh);   // wire 0 -> bit 3
    __sincosf(0.5f * a.y, &sh, &ch); rx_bit<2>(sr, si, ch, sh);
    __sincosf(0.5f * a.z, &sh, &ch); rx_bit<1>(sr, si, ch, sh);
    __sincosf(0.5f * a.w, &sh, &ch); rx_bit<0>(sr, si, ch, sh);
}

__device__ __forceinline__ void layer(float sr[DIM], float si[DIM], float4 w) {
    float ch, sh;
    __sincosf(0.5f * w.x, &sh, &ch); rx_bit<3>(sr, si, ch, sh);
    __sincosf(0.5f * w.y, &sh, &ch); rx_bit<2>(sr, si, ch, sh);
    __sincosf(0.5f * w.z, &sh, &ch); rx_bit<1>(sr, si, ch, sh);
    __sincosf(0.5f * w.w, &sh, &ch); rx_bit<0>(sr, si, ch, sh);
    cnot_g<3,2>(sr, si);
    cnot_g<2,1>(sr, si);
    cnot_g<1,0>(sr, si);
    cnot_g<0,3>(sr, si);
}

__device__ __forceinline__ float4 measure(const float sr[DIM], const float si[DIM]) {
    float e0 = 0.f, e1 = 0.f, e2 = 0.f, e3 = 0.f;
    #pragma unroll
    for (int i = 0; i < DIM; ++i) {
        float p = fmaf(sr[i], sr[i], si[i] * si[i]);
        e0 += (i & 8) ? -p : p;
        e1 += (i & 4) ? -p : p;
        e2 += (i & 2) ? -p : p;
        e3 += (i & 1) ? -p : p;
    }
    return make_float4(e0, e1, e2, e3);
}

// ---------------- kernel 1: Q,K,V circuits (split over blockIdx.y) ---------

__global__ __launch_bounds__(256) void qkv_kernel(
        const float* __restrict__ x,
        const float* __restrict__ wQp, const float* __restrict__ wKp,
        const float* __restrict__ wVp,
        float4* __restrict__ Q, float4* __restrict__ KV) {
    const int i = blockIdx.x * 256 + threadIdx.x;
    const int which = blockIdx.y;          // 0=Q, 1=K, 2=V
    const float4 xv = ((const float4*)x)[i];
    const float* wp = (which == 0) ? wQp : (which == 1) ? wKp : wVp;
    const float4 w = *(const float4*)wp;

    float sr[DIM], si[DIM];
    embed(sr, si, xv);
    layer(sr, si, w);
    const float4 r = measure(sr, si);

    if (which == 0)      Q[i]          = r;
    else if (which == 1) KV[2 * i]     = r;   // K interleaved with V
    else                 KV[2 * i + 1] = r;
}

// ---------------- kernel 2: attention partials -----------------------------
// Block = 256 threads. Stages one 512-key chunk of K/V into LDS (16 KB),
// processes 256 rows against it (1 row/thread, wave-uniform broadcast
// reads from LDS). Grid = (n/256 row-groups, 4 key-chunks).
// Partials (den, ctx) written to workspace.

__global__ __launch_bounds__(256) void attn_partial(
        const float4* __restrict__ Q, const float4* __restrict__ KV,
        float* __restrict__ pden, float4* __restrict__ pctx, int n) {
    __shared__ float4 kvs[2 * CHUNK];   // 16 KB

    const int rg = blockIdx.x;          // row-group (256 rows each)
    const int c  = blockIdx.y;          // key chunk
    const int b  = rg >> 3;             // 8 row-groups per batch (2048 rows)

    const float4* src = KV + (size_t)b * (2 * SEQ) + c * (2 * CHUNK);
    for (int t = threadIdx.x; t < 2 * CHUNK; t += 256)
        kvs[t] = src[t];
    __syncthreads();

    const int row = rg * 256 + threadIdx.x;
    const float4 q = Q[row];
    // fold 0.5 (1/sqrt(E)) * log2(e) so the loop uses exp2 directly
    const float SC = 0.72134752044f;
    const float qx = q.x * SC, qy = q.y * SC, qz = q.z * SC, qw = q.w * SC;

    float den = 0.f, a0 = 0.f, a1 = 0.f, a2 = 0.f, a3 = 0.f;
    #pragma unroll 8
    for (int k = 0; k < CHUNK; ++k) {
        const float4 kv = kvs[2 * k];       // wave-uniform -> LDS broadcast
        const float4 vv = kvs[2 * k + 1];
        float s = fmaf(qx, kv.x, fmaf(qy, kv.y, fmaf(qz, kv.z, qw * kv.w)));
        float e = exp2f(s);                 // s in [-2.89,2.89]: no max needed
        den += e;
        a0 = fmaf(e, vv.x, a0);
        a1 = fmaf(e, vv.y, a1);
        a2 = fmaf(e, vv.z, a2);
        a3 = fmaf(e, vv.w, a3);
    }

    pden[c * n + row] = den;                          // coalesced
    pctx[c * n + row] = make_float4(a0, a1, a2, a3);  // coalesced
}

// ---------------- kernel 3: combine partials + final circuit ---------------

__global__ __launch_bounds__(256) void combine_kernel(
        const float* __restrict__ pden, const float4* __restrict__ pctx,
        const float* __restrict__ wCp, float4* __restrict__ out, int n) {
    const int row = blockIdx.x * 256 + threadIdx.x;

    float d = 0.f;
    float c0 = 0.f, c1 = 0.f, c2 = 0.f, c3 = 0.f;
    #pragma unroll
    for (int c = 0; c < NCHUNK; ++c) {
        d += pden[c * n + row];
        const float4 p = pctx[c * n + row];
        c0 += p.x; c1 += p.y; c2 += p.z; c3 += p.w;
    }
    const float inv = 1.0f / d;
    const float4 ctx = make_float4(c0 * inv, c1 * inv, c2 * inv, c3 * inv);

    const float4 wC = *(const float4*)wCp;
    float sr[DIM], si[DIM];
    embed(sr, si, ctx);
    layer(sr, si, wC);
    out[row] = measure(sr, si);
}

// ---------------- launch ---------------------------------------------------

extern "C" void kernel_launch(void* const* d_in, const int* in_sizes, int n_in,
                              void* d_out, int out_size, void* d_ws, size_t ws_size,
                              hipStream_t stream) {
    const float* x  = (const float*)d_in[0];
    const float* wQ = (const float*)d_in[1];
    const float* wK = (const float*)d_in[2];
    const float* wV = (const float*)d_in[3];
    const float* wC = (const float*)d_in[4];

    const int n = in_sizes[0] / 4;            // B*S = 65536 rows
    float4* Q    = (float4*)d_ws;             // n float4        = 1 MB
    float4* KV   = Q + n;                     // 2n float4       = 2 MB
    float4* pctx = KV + 2 * n;                // 4n float4       = 4 MB
    float*  pden = (float*)(pctx + 4 * n);    // 4n float        = 1 MB

    dim3 qgrid(n / 256, 3);
    qkv_kernel<<<qgrid, 256, 0, stream>>>(x, wQ, wK, wV, Q, KV);

    dim3 agrid(n / 256, NCHUNK);              // (256, 4) = 1024 blocks
    attn_partial<<<agrid, 256, 0, stream>>>(Q, KV, pden, pctx, n);

    combine_kernel<<<n / 256, 256, 0, stream>>>(pden, pctx, wC, (float4*)d_out, n);
}

// Round 4
// 104.668 us; speedup vs baseline: 1.7521x; 1.1787x over previous
//
#include <hip/hip_runtime.h>

#define DIM 16
#define SEQ 2048
#define CHUNK 256            // keys per block chunk
#define NCHUNK 8             // SEQ / CHUNK
#define RPT 4                // query rows per thread

typedef float v2f __attribute__((ext_vector_type(2)));

static __device__ __forceinline__ float fexp2(float x) {
#if __has_builtin(__builtin_amdgcn_exp2f)
    return __builtin_amdgcn_exp2f(x);   // raw v_exp_f32; inputs in [-2.9,2.9]
#else
    return exp2f(x);
#endif
}

// ---------------- quantum circuit primitives (all register-resident) --------

template<int P>
__device__ __forceinline__ void rx_bit(float sr[DIM], float si[DIM], float ch, float sh) {
    constexpr int m = 1 << P;
    #pragma unroll
    for (int i = 0; i < DIM; ++i) {
        if ((i & m) == 0) {
            const int j = i | m;
            float r0 = sr[i], i0 = si[i], r1 = sr[j], i1 = si[j];
            sr[i] = fmaf(ch, r0,  sh * i1);
            si[i] = fmaf(ch, i0, -sh * r1);
            sr[j] = fmaf(ch, r1,  sh * i0);
            si[j] = fmaf(ch, i1, -sh * r0);
        }
    }
}

template<int PC, int PT>
__device__ __forceinline__ void cnot_g(float sr[DIM], float si[DIM]) {
    constexpr int cm = 1 << PC, tm = 1 << PT;
    #pragma unroll
    for (int i = 0; i < DIM; ++i) {
        if ((i & cm) && !(i & tm)) {
            const int j = i | tm;
            float t;
            t = sr[i]; sr[i] = sr[j]; sr[j] = t;
            t = si[i]; si[i] = si[j]; si[j] = t;
        }
    }
}

__device__ __forceinline__ void embed(float sr[DIM], float si[DIM], float4 a) {
    #pragma unroll
    for (int i = 0; i < DIM; ++i) { sr[i] = 0.f; si[i] = 0.f; }
    sr[0] = 1.f;
    float ch, sh;
    __sincosf(0.5f * a.x, &sh, &ch); rx_bit<3>(sr, si, ch, sh);   // wire 0 -> bit 3
    __sincosf(0.5f * a.y, &sh, &ch); rx_bit<2>(sr, si, ch, sh);
    __sincosf(0.5f * a.z, &sh, &ch); rx_bit<1>(sr, si, ch, sh);
    __sincosf(0.5f * a.w, &sh, &ch); rx_bit<0>(sr, si, ch, sh);
}

__device__ __forceinline__ void layer(float sr[DIM], float si[DIM], float4 w) {
    float ch, sh;
    __sincosf(0.5f * w.x, &sh, &ch); rx_bit<3>(sr, si, ch, sh);
    __sincosf(0.5f * w.y, &sh, &ch); rx_bit<2>(sr, si, ch, sh);
    __sincosf(0.5f * w.z, &sh, &ch); rx_bit<1>(sr, si, ch, sh);
    __sincosf(0.5f * w.w, &sh, &ch); rx_bit<0>(sr, si, ch, sh);
    cnot_g<3,2>(sr, si);
    cnot_g<2,1>(sr, si);
    cnot_g<1,0>(sr, si);
    cnot_g<0,3>(sr, si);
}

__device__ __forceinline__ float4 measure(const float sr[DIM], const float si[DIM]) {
    float e0 = 0.f, e1 = 0.f, e2 = 0.f, e3 = 0.f;
    #pragma unroll
    for (int i = 0; i < DIM; ++i) {
        float p = fmaf(sr[i], sr[i], si[i] * si[i]);
        e0 += (i & 8) ? -p : p;
        e1 += (i & 4) ? -p : p;
        e2 += (i & 2) ? -p : p;
        e3 += (i & 1) ? -p : p;
    }
    return make_float4(e0, e1, e2, e3);
}

// ---------------- kernel 1: Q,K,V circuits (split over blockIdx.y) ---------

__global__ __launch_bounds__(256) void qkv_kernel(
        const float* __restrict__ x,
        const float* __restrict__ wQp, const float* __restrict__ wKp,
        const float* __restrict__ wVp,
        float4* __restrict__ Q, float4* __restrict__ KV) {
    const int i = blockIdx.x * 256 + threadIdx.x;
    const int which = blockIdx.y;          // 0=Q, 1=K, 2=V
    const float4 xv = ((const float4*)x)[i];
    const float* wp = (which == 0) ? wQp : (which == 1) ? wKp : wVp;
    const float4 w = *(const float4*)wp;

    float sr[DIM], si[DIM];
    embed(sr, si, xv);
    layer(sr, si, w);
    const float4 r = measure(sr, si);

    if (which == 0)      Q[i]          = r;
    else if (which == 1) KV[2 * i]     = r;   // K interleaved with V
    else                 KV[2 * i + 1] = r;
}

// ---------------- kernel 2: attention partials -----------------------------
// Block = 256 threads. Stages one 256-key chunk of K/V in LDS (8 KB).
// Each thread processes RPT=4 query rows against the chunk: the 2 LDS
// broadcast reads per key are amortized over 4 rows (LDS return-bus was
// the round-3 bottleneck). Packed fp32 (v_pk_fma_f32) for dot + accum.

__global__ __launch_bounds__(256) void attn_partial(
        const float4* __restrict__ Q, const float4* __restrict__ KV,
        float* __restrict__ pden, float4* __restrict__ pctx, int n) {
    __shared__ float4 kvs[2 * CHUNK];   // 8 KB

    const int rg = blockIdx.x;          // row-group: 1024 rows
    const int c  = blockIdx.y;          // key chunk
    const int b  = rg >> 1;             // 2 row-groups per batch

    const float4* src = KV + (size_t)b * (2 * SEQ) + c * (2 * CHUNK);
    for (int t = threadIdx.x; t < 2 * CHUNK; t += 256)
        kvs[t] = src[t];
    __syncthreads();

    // fold 0.5 (1/sqrt(E)) * log2(e): loop uses raw exp2
    const float SC = 0.72134752044f;
    const int row0 = rg * (256 * RPT) + threadIdx.x;

    v2f qa[RPT], qb[RPT];
    #pragma unroll
    for (int j = 0; j < RPT; ++j) {
        const float4 q = Q[row0 + j * 256];
        qa[j] = (v2f){q.x * SC, q.y * SC};
        qb[j] = (v2f){q.z * SC, q.w * SC};
    }

    float den[RPT];
    v2f a01[RPT], a23[RPT];
    #pragma unroll
    for (int j = 0; j < RPT; ++j) {
        den[j] = 0.f;
        a01[j] = (v2f){0.f, 0.f};
        a23[j] = (v2f){0.f, 0.f};
    }

    #pragma unroll 4
    for (int k = 0; k < CHUNK; ++k) {
        const float4 kv = kvs[2 * k];       // wave-uniform -> broadcast
        const float4 vv = kvs[2 * k + 1];
        const v2f ka = (v2f){kv.x, kv.y}, kb = (v2f){kv.z, kv.w};
        const v2f va = (v2f){vv.x, vv.y}, vb = (v2f){vv.z, vv.w};
        #pragma unroll
        for (int j = 0; j < RPT; ++j) {
            v2f t = __builtin_elementwise_fma(qb[j], kb, qa[j] * ka);
            float e = fexp2(t.x + t.y);
            v2f e2 = (v2f){e, e};
            a01[j] = __builtin_elementwise_fma(e2, va, a01[j]);
            a23[j] = __builtin_elementwise_fma(e2, vb, a23[j]);
            den[j] += e;
        }
    }

    #pragma unroll
    for (int j = 0; j < RPT; ++j) {
        const int row = row0 + j * 256;
        pden[c * n + row] = den[j];
        pctx[c * n + row] = make_float4(a01[j].x, a01[j].y, a23[j].x, a23[j].y);
    }
}

// ---------------- kernel 3: combine partials + final circuit ---------------

__global__ __launch_bounds__(256) void combine_kernel(
        const float* __restrict__ pden, const float4* __restrict__ pctx,
        const float* __restrict__ wCp, float4* __restrict__ out, int n) {
    const int row = blockIdx.x * 256 + threadIdx.x;

    float d = 0.f;
    float c0 = 0.f, c1 = 0.f, c2 = 0.f, c3 = 0.f;
    #pragma unroll
    for (int c = 0; c < NCHUNK; ++c) {
        d += pden[c * n + row];
        const float4 p = pctx[c * n + row];
        c0 += p.x; c1 += p.y; c2 += p.z; c3 += p.w;
    }
    const float inv = 1.0f / d;
    const float4 ctx = make_float4(c0 * inv, c1 * inv, c2 * inv, c3 * inv);

    const float4 wC = *(const float4*)wCp;
    float sr[DIM], si[DIM];
    embed(sr, si, ctx);
    layer(sr, si, wC);
    out[row] = measure(sr, si);
}

// ---------------- launch ---------------------------------------------------

extern "C" void kernel_launch(void* const* d_in, const int* in_sizes, int n_in,
                              void* d_out, int out_size, void* d_ws, size_t ws_size,
                              hipStream_t stream) {
    const float* x  = (const float*)d_in[0];
    const float* wQ = (const float*)d_in[1];
    const float* wK = (const float*)d_in[2];
    const float* wV = (const float*)d_in[3];
    const float* wC = (const float*)d_in[4];

    const int n = in_sizes[0] / 4;            // B*S = 65536 rows
    float4* Q    = (float4*)d_ws;             // n float4          = 1 MB
    float4* KV   = Q + n;                     // 2n float4         = 2 MB
    float4* pctx = KV + 2 * n;                // NCHUNK*n float4   = 8 MB
    float*  pden = (float*)(pctx + NCHUNK * n); // NCHUNK*n float  = 2 MB

    dim3 qgrid(n / 256, 3);
    qkv_kernel<<<qgrid, 256, 0, stream>>>(x, wQ, wK, wV, Q, KV);

    dim3 agrid(n / (256 * RPT), NCHUNK);      // (64, 8) = 512 blocks
    attn_partial<<<agrid, 256, 0, stream>>>(Q, KV, pden, pctx, n);

    combine_kernel<<<n / 256, 256, 0, stream>>>(pden, pctx, wC, (float4*)d_out, n);
}